// Round 12
// baseline (143.894 us; speedup 1.0000x reference)
//
#include <hip/hip_runtime.h>
#include <hip/hip_bf16.h>

constexpr int B = 2, S = 2048, D = 1024, H = 16, Hd = 64;
constexpr int M = B * S;   // 4096 rows
constexpr int K = 1024;

typedef __attribute__((ext_vector_type(8))) short short8;
typedef __attribute__((ext_vector_type(4))) float f32x4;

__device__ __forceinline__ float bf2f(unsigned short u) {
    return __uint_as_float(((unsigned)u) << 16);
}
__device__ __forceinline__ unsigned short f2bf(float f) {   // RNE
    unsigned u = __float_as_uint(f);
    u += 0x7FFF + ((u >> 16) & 1);
    return (unsigned short)(u >> 16);
}
__device__ __forceinline__ void gload_lds16(const unsigned short* g, unsigned short* l) {
    __builtin_amdgcn_global_load_lds(
        (const __attribute__((address_space(1))) void*)g,
        (__attribute__((address_space(3))) void*)l, 16, 0, 0);
}

// ---------------------------------------------------------------------------
// Prep: z=0..3 -> weight transpose+convert (w [K,N] fp32 -> wt [N,K] bf16);
//       z=4    -> x fp32 -> bf16 (grid-stride, 8 elems/thread/iter).
// ---------------------------------------------------------------------------
__global__ __launch_bounds__(256) void prep_kernel(
    const float* __restrict__ x,
    const float* __restrict__ wq, const float* __restrict__ wk,
    const float* __restrict__ wv, const float* __restrict__ wo,
    unsigned short* __restrict__ xb,
    unsigned short* __restrict__ wqkv_t, unsigned short* __restrict__ wo_t)
{
    __shared__ float tile[64][65];
    const int z = blockIdx.z;
    const int t = threadIdx.x;
    if (z == 4) {   // x conversion: 256 blocks x 256 thr x 8 iters x 8 elems
        const int bid = blockIdx.y * 16 + blockIdx.x;
        const size_t base_i = ((size_t)bid * 256 + t) * 8;
        #pragma unroll
        for (int it = 0; it < 8; ++it) {
            const size_t i = base_i + (size_t)it * 524288;
            float4 a = *(const float4*)(x + i), b = *(const float4*)(x + i + 4);
            ushort4 u0 = {f2bf(a.x), f2bf(a.y), f2bf(a.z), f2bf(a.w)};
            ushort4 u1 = {f2bf(b.x), f2bf(b.y), f2bf(b.z), f2bf(b.w)};
            *(ushort4*)(xb + i) = u0;
            *(ushort4*)(xb + i + 4) = u1;
        }
        return;
    }
    const float* w = (z == 0) ? wq : (z == 1) ? wk : (z == 2) ? wv : wo;
    unsigned short* dst = (z == 3) ? wo_t : wqkv_t + (size_t)z * K * K;
    const int k0 = blockIdx.x * 64, n0 = blockIdx.y * 64;
    #pragma unroll
    for (int it = 0; it < 16; ++it) {
        int idx = t + it * 256;
        tile[idx >> 6][idx & 63] = w[(size_t)(k0 + (idx >> 6)) * K + n0 + (idx & 63)];
    }
    __syncthreads();
    #pragma unroll
    for (int it = 0; it < 16; ++it) {
        int idx = t + it * 256;
        int r = idx >> 6, c = idx & 63;
        dst[(size_t)(n0 + r) * K + k0 + c] = f2bf(tile[c][r]);
    }
}

// ---------------------------------------------------------------------------
// Fused QKV MFMA GEMM, 2-phase pipelined + XCD swizzle (T1).
// Q written PRE-SCALED by 0.125*log2(e) (exp2-domain attention).
// ---------------------------------------------------------------------------
__global__ __launch_bounds__(256) void qkv_mfma_kernel(
    const unsigned short* __restrict__ xa, const unsigned short* __restrict__ bt,
    unsigned short* __restrict__ q, unsigned short* __restrict__ k,
    unsigned short* __restrict__ vt)
{
    __shared__ unsigned short A_lds[2][128][32];
    __shared__ unsigned short B_lds[2][128][32];
    const int t = threadIdx.x, w = t >> 6, l = t & 63;
    const int lr = l & 15, lg = l >> 4;
    const int wm = w >> 1, wn = w & 1;
    // XCD swizzle: 768 blocks = 8 XCDs x 96; each XCD gets 3 n-panels x 32 m
    const int lin = ((int)blockIdx.x & 7) * 96 + ((int)blockIdx.x >> 3);
    const int m0 = (lin & 31) * 128, n0 = (lin >> 5) * 128;
    const int srow = l >> 2, skofs = (l & 3) * 8;

    f32x4 acc[4][4];
    #pragma unroll
    for (int i = 0; i < 4; ++i)
        #pragma unroll
        for (int j = 0; j < 4; ++j) acc[i][j] = (f32x4){0.f, 0.f, 0.f, 0.f};

    #pragma unroll
    for (int p = 0; p < 2; ++p) {
        const int c = w * 2 + p;
        gload_lds16(xa + (size_t)(m0 + c * 16 + srow) * K + skofs, &A_lds[0][c * 16][0]);
        gload_lds16(bt + (size_t)(n0 + c * 16 + srow) * K + skofs, &B_lds[0][c * 16][0]);
    }
    __syncthreads();

    int cur = 0;
    for (int k0 = 0; k0 < K; k0 += 32) {
        if (k0 + 32 < K) {
            #pragma unroll
            for (int p = 0; p < 2; ++p) {
                const int c = w * 2 + p;
                gload_lds16(xa + (size_t)(m0 + c * 16 + srow) * K + k0 + 32 + skofs,
                            &A_lds[cur ^ 1][c * 16][0]);
                gload_lds16(bt + (size_t)(n0 + c * 16 + srow) * K + k0 + 32 + skofs,
                            &B_lds[cur ^ 1][c * 16][0]);
            }
        }
        short8 af[4], bf[4];
        #pragma unroll
        for (int i = 0; i < 4; ++i) af[i] = *(const short8*)&A_lds[cur][wm * 64 + i * 16 + lr][lg * 8];
        #pragma unroll
        for (int j = 0; j < 4; ++j) bf[j] = *(const short8*)&B_lds[cur][wn * 64 + j * 16 + lr][lg * 8];
        #pragma unroll
        for (int i = 0; i < 4; ++i)
            #pragma unroll
            for (int j = 0; j < 4; ++j)
                acc[i][j] = __builtin_amdgcn_mfma_f32_16x16x32_bf16(af[i], bf[j], acc[i][j], 0, 0, 0);
        __syncthreads();
        cur ^= 1;
    }

    const int z = (n0 >> 10);
    const float scale = (z == 0) ? 0.125f * 1.44269504f : 1.0f;
    #pragma unroll
    for (int i = 0; i < 4; ++i) {
        const int mbase = m0 + wm * 64 + i * 16 + lg * 4;
        #pragma unroll
        for (int j = 0; j < 4; ++j) {
            const int n = n0 + wn * 64 + j * 16 + lr;
            const int nn = n & 1023, hh = nn >> 6, hd = nn & 63;
            #pragma unroll
            for (int r = 0; r < 4; ++r) {
                const int mm = mbase + r, bb = mm >> 11, ss = mm & (S - 1);
                const unsigned short val = f2bf(acc[i][j][r] * scale);
                if (z == 0)      q[((size_t)(bb * H + hh) * S + ss) * Hd + hd] = val;
                else if (z == 1) k[((size_t)(bb * H + hh) * S + ss) * Hd + hd] = val;
                else             vt[((size_t)(bb * H + hh) * Hd + hd) * S + ss] = val;
            }
        }
    }
}

// ---------------------------------------------------------------------------
// Output projection MFMA GEMM, 2-phase pipelined + XCD swizzle.
// ---------------------------------------------------------------------------
__global__ __launch_bounds__(256) void out_mfma_kernel(
    const unsigned short* __restrict__ a, const unsigned short* __restrict__ bt,
    const float* __restrict__ bias, float* __restrict__ out)
{
    __shared__ unsigned short A_lds[2][128][32];
    __shared__ unsigned short B_lds[2][128][32];
    const int t = threadIdx.x, w = t >> 6, l = t & 63;
    const int lr = l & 15, lg = l >> 4;
    const int wm = w >> 1, wn = w & 1;
    // XCD swizzle: 256 blocks = 8 XCDs x 32; each XCD gets one n-panel
    const int lin = ((int)blockIdx.x & 7) * 32 + ((int)blockIdx.x >> 3);
    const int m0 = (lin & 31) * 128, n0 = (lin >> 5) * 128;
    const int srow = l >> 2, skofs = (l & 3) * 8;

    f32x4 acc[4][4];
    #pragma unroll
    for (int i = 0; i < 4; ++i)
        #pragma unroll
        for (int j = 0; j < 4; ++j) acc[i][j] = (f32x4){0.f, 0.f, 0.f, 0.f};

    #pragma unroll
    for (int p = 0; p < 2; ++p) {
        const int c = w * 2 + p;
        gload_lds16(a  + (size_t)(m0 + c * 16 + srow) * K + skofs, &A_lds[0][c * 16][0]);
        gload_lds16(bt + (size_t)(n0 + c * 16 + srow) * K + skofs, &B_lds[0][c * 16][0]);
    }
    __syncthreads();

    int cur = 0;
    for (int k0 = 0; k0 < K; k0 += 32) {
        if (k0 + 32 < K) {
            #pragma unroll
            for (int p = 0; p < 2; ++p) {
                const int c = w * 2 + p;
                gload_lds16(a  + (size_t)(m0 + c * 16 + srow) * K + k0 + 32 + skofs,
                            &A_lds[cur ^ 1][c * 16][0]);
                gload_lds16(bt + (size_t)(n0 + c * 16 + srow) * K + k0 + 32 + skofs,
                            &B_lds[cur ^ 1][c * 16][0]);
            }
        }
        short8 af[4], bf[4];
        #pragma unroll
        for (int i = 0; i < 4; ++i) af[i] = *(const short8*)&A_lds[cur][wm * 64 + i * 16 + lr][lg * 8];
        #pragma unroll
        for (int j = 0; j < 4; ++j) bf[j] = *(const short8*)&B_lds[cur][wn * 64 + j * 16 + lr][lg * 8];
        #pragma unroll
        for (int i = 0; i < 4; ++i)
            #pragma unroll
            for (int j = 0; j < 4; ++j)
                acc[i][j] = __builtin_amdgcn_mfma_f32_16x16x32_bf16(af[i], bf[j], acc[i][j], 0, 0, 0);
        __syncthreads();
        cur ^= 1;
    }

    #pragma unroll
    for (int i = 0; i < 4; ++i) {
        const int mbase = m0 + wm * 64 + i * 16 + lg * 4;
        #pragma unroll
        for (int j = 0; j < 4; ++j) {
            const int n = n0 + wn * 64 + j * 16 + lr;
            const float bv = bias[n];
            #pragma unroll
            for (int r = 0; r < 4; ++r)
                out[(size_t)(mbase + r) * D + n] = acc[i][j][r] + bv;
        }
    }
}

// ---------------------------------------------------------------------------
// MFMA causal flash attention, v8:
//  - XCD-locality grid (proven R11: FETCH 62->12 MB).
//  - K/V DOUBLE-buffered via global_load_lds direct (no reg staging, no
//    publish ds_writes) -> ONE __syncthreads per k-tile (its vmcnt-drain is
//    the needed wait; loads had the whole compute phase to land).
//  - P_lds XOR-swizzled [4][16][64] -> total LDS exactly 40 KB = 4 blocks/CU
//    (grid-capped residency unchanged).
//  - swapped QK^T + swapped PV (lane-local scalar softmax), exp2 domain,
//    defer-max THR=8, packed-b64 P, setprio, XOR-swizzled K/V reads.
// ---------------------------------------------------------------------------
__device__ __forceinline__ void stage64(const unsigned short* __restrict__ g0,
                                        size_t gstride, unsigned short* lbuf,
                                        int w, int l) {
    #pragma unroll
    for (int it = 0; it < 2; ++it) {
        const int chunk = w * 2 + it;
        const int row = chunk * 8 + (l >> 3);
        const int scol = ((l & 7) ^ (row & 7)) * 8;   // inverse-swizzled source
        gload_lds16(g0 + (size_t)row * gstride + scol, lbuf + chunk * 512);
    }
}

__global__ __launch_bounds__(256) void attn_mfma_kernel(
    const unsigned short* __restrict__ q, const unsigned short* __restrict__ k,
    const unsigned short* __restrict__ vt, unsigned short* __restrict__ ctx)
{
    __shared__ unsigned short Kb[2][64 * 64];
    __shared__ unsigned short Vb[2][64 * 64];
    __shared__ unsigned short P_lds[4][16 * 64];
    const int t = threadIdx.x, w = t >> 6, l = t & 63;
    const int lr = l & 15, lg = l >> 4;

    // XCD-locality decomposition (R11)
    const int bid = blockIdx.x;          // 0..1023
    const int xcd = bid & 7;
    const int j   = bid >> 3;            // 0..127
    const int m   = j >> 5;              // 0..3: bh-group within XCD
    const int c   = j & 31;
    const int bh  = xcd * 4 + m;         // 0..31
    const int bb  = bh >> 4, hh = bh & 15;
    const int qt  = (m & 1) ? (31 - c) : c;   // exact per-CU balance

    const int q0 = qt * 64 + w * 16;
    const int diag = qt;
    const size_t base  = (size_t)(bb * H + hh) * S * Hd;
    const size_t vbase = (size_t)(bb * H + hh) * Hd * S;
    const int pswz = (lr & 7) << 3;      // P_lds XOR swizzle (ush units)

    short8 qf[2];
    #pragma unroll
    for (int cc = 0; cc < 2; ++cc)
        qf[cc] = *(const short8*)(q + base + (size_t)(q0 + lr) * Hd + cc * 32 + lg * 8);

    f32x4 accO[4];   // O^T: accO[hb][r] = O^T[hb*16+lg*4+r][q=lr]
    #pragma unroll
    for (int hb = 0; hb < 4; ++hb) accO[hb] = (f32x4){0.f, 0.f, 0.f, 0.f};
    float m_run = -INFINITY, l_run = 0.f;   // lane-local: q-col lr

    // prologue: tile 0 -> buf 0
    stage64(k + base, Hd, Kb[0], w, l);
    stage64(vt + vbase, S, Vb[0], w, l);
    __syncthreads();

    int cur = 0;
    for (int kt = 0; kt <= diag; ++kt) {
        // ---- prefetch next tile straight into the other LDS buffer ----
        if (kt < diag) {
            stage64(k + base + (size_t)(kt + 1) * 64 * Hd, Hd, Kb[cur ^ 1], w, l);
            stage64(vt + vbase + (size_t)(kt + 1) * 64, S, Vb[cur ^ 1], w, l);
        }

        const unsigned short* Kc = Kb[cur];
        const unsigned short* Vc = Vb[cur];

        // ---- S^T = K Q^T ----
        f32x4 accS[4];
        __builtin_amdgcn_s_setprio(1);
        #pragma unroll
        for (int kc = 0; kc < 4; ++kc) {
            accS[kc] = (f32x4){0.f, 0.f, 0.f, 0.f};
            const int krow = kc * 16 + lr;
            #pragma unroll
            for (int cc = 0; cc < 2; ++cc) {
                short8 kf = *(const short8*)&Kc[krow * 64 +
                    ((cc * 32 + lg * 8) ^ ((krow & 7) * 8))];
                accS[kc] = __builtin_amdgcn_mfma_f32_16x16x32_bf16(kf, qf[cc], accS[kc], 0, 0, 0);
            }
        }
        __builtin_amdgcn_s_setprio(0);

        // ---- online softmax (exp2 domain, defer-max, lane-local) ----
        float ps[16];
        #pragma unroll
        for (int kc = 0; kc < 4; ++kc)
            #pragma unroll
            for (int r = 0; r < 4; ++r) {
                float s = accS[kc][r];
                if (kt == diag && (kc * 16 + lg * 4 + r > w * 16 + lr)) s = -INFINITY;
                ps[kc * 4 + r] = s;
            }
        float m8[8];
        #pragma unroll
        for (int i = 0; i < 8; ++i) m8[i] = fmaxf(ps[i], ps[i + 8]);
        float m4a = fmaxf(m8[0], m8[4]), m4b = fmaxf(m8[1], m8[5]);
        float m4c = fmaxf(m8[2], m8[6]), m4d = fmaxf(m8[3], m8[7]);
        float mloc = fmaxf(fmaxf(m4a, m4b), fmaxf(m4c, m4d));
        mloc = fmaxf(mloc, __shfl_xor(mloc, 16));
        mloc = fmaxf(mloc, __shfl_xor(mloc, 32));

        const bool resc = __any(mloc > m_run + 8.f);
        const float mn = resc ? fmaxf(m_run, mloc) : m_run;

        #pragma unroll
        for (int i = 0; i < 16; ++i) ps[i] = exp2f(ps[i] - mn);
        float s8[8];
        #pragma unroll
        for (int i = 0; i < 8; ++i) s8[i] = ps[i] + ps[i + 8];
        float rs = ((s8[0] + s8[4]) + (s8[1] + s8[5])) +
                   ((s8[2] + s8[6]) + (s8[3] + s8[7]));
        rs += __shfl_xor(rs, 16);
        rs += __shfl_xor(rs, 32);

        if (resc) {
            const float sfc = exp2f(m_run - mn);
            l_run = l_run * sfc + rs;
            m_run = mn;
            #pragma unroll
            for (int hb = 0; hb < 4; ++hb)
                #pragma unroll
                for (int r = 0; r < 4; ++r) accO[hb][r] *= sfc;
        } else {
            l_run += rs;
        }

        // ---- P -> per-wave LDS (swizzled), re-read as B-frags ----
        #pragma unroll
        for (int kc = 0; kc < 4; ++kc) {
            uint2 pk;
            *(__hip_bfloat162*)&pk.x =
                __float22bfloat162_rn(make_float2(ps[kc * 4 + 0], ps[kc * 4 + 1]));
            *(__hip_bfloat162*)&pk.y =
                __float22bfloat162_rn(make_float2(ps[kc * 4 + 2], ps[kc * 4 + 3]));
            *(uint2*)&P_lds[w][lr * 64 + ((kc * 16 + lg * 4) ^ pswz)] = pk;
        }
        short8 pa[2];
        #pragma unroll
        for (int cc = 0; cc < 2; ++cc)
            pa[cc] = *(const short8*)&P_lds[w][lr * 64 + ((cc * 32 + lg * 8) ^ pswz)];

        // ---- O^T += V^T P^T ----
        __builtin_amdgcn_s_setprio(1);
        #pragma unroll
        for (int hb = 0; hb < 4; ++hb) {
            const int vrow = hb * 16 + lr;
            #pragma unroll
            for (int cc = 0; cc < 2; ++cc) {
                short8 vf = *(const short8*)&Vc[vrow * 64 +
                    ((cc * 32 + lg * 8) ^ ((vrow & 7) * 8))];
                accO[hb] = __builtin_amdgcn_mfma_f32_16x16x32_bf16(vf, pa[cc], accO[hb], 0, 0, 0);
            }
        }
        __builtin_amdgcn_s_setprio(0);

        // ---- single barrier: drains prefetch vmcnt + guards buffer swap ----
        __syncthreads();
        cur ^= 1;
    }

    // ---- epilogue: lane owns q-row q0+lr entirely; 4 x 8B stores ----
    const float inv = 1.f / l_run;
    unsigned short* crow = ctx + (size_t)(bb * S + q0 + lr) * D + hh * Hd + lg * 4;
    #pragma unroll
    for (int hb = 0; hb < 4; ++hb) {
        ushort4 o;
        o.x = f2bf(accO[hb][0] * inv);
        o.y = f2bf(accO[hb][1] * inv);
        o.z = f2bf(accO[hb][2] * inv);
        o.w = f2bf(accO[hb][3] * inv);
        *(ushort4*)(crow + hb * 16) = o;
    }
}

extern "C" void kernel_launch(void* const* d_in, const int* in_sizes, int n_in,
                              void* d_out, int out_size, void* d_ws, size_t ws_size,
                              hipStream_t stream) {
    const float* x  = (const float*)d_in[0];
    const float* wq = (const float*)d_in[1];
    const float* wk = (const float*)d_in[2];
    const float* wv = (const float*)d_in[3];
    const float* wo = (const float*)d_in[4];
    const float* bo = (const float*)d_in[5];
    float* out = (float*)d_out;

    char* ws = (char*)d_ws;
    unsigned short* x_bf   = (unsigned short*)ws;
    unsigned short* q      = (unsigned short*)(ws + ((size_t)8  << 20));
    unsigned short* kk     = (unsigned short*)(ws + ((size_t)16 << 20));
    unsigned short* vt     = (unsigned short*)(ws + ((size_t)24 << 20));
    unsigned short* ctx    = x_bf;
    unsigned short* wqkv_t = (unsigned short*)(ws + ((size_t)32 << 20));
    unsigned short* wo_t   = (unsigned short*)(ws + ((size_t)38 << 20));

    dim3 gprep(16, 16, 5);
    prep_kernel<<<gprep, 256, 0, stream>>>(x, wq, wk, wv, wo, x_bf, wqkv_t, wo_t);

    qkv_mfma_kernel<<<768, 256, 0, stream>>>(x_bf, wqkv_t, q, kk, vt);

    attn_mfma_kernel<<<1024, 256, 0, stream>>>(q, kk, vt, ctx);

    out_mfma_kernel<<<256, 256, 0, stream>>>(ctx, wo_t, bo, out);
}